// Round 2
// baseline (146.243 us; speedup 1.0000x reference)
//
#include <hip/hip_runtime.h>

// Problem constants (fixed by the reference)
#define NN 2048   // nodes
#define FF 64     // features
#define HH 64     // hidden
#define CC 8      // classes
#define NB 2      // nodes per wave in g_kernel

#define INF __builtin_inff()

// ws layout (floats): T[64] @0, A[65] @64, B[65] @129, g[NN*CC] @256
#define WS_T 0
#define WS_A 64
#define WS_B 129
#define WS_G 256

// ---------------------------------------------------------------------------
// Kernel P: collapse the distance MLP m(d)=bm2+sum_h Wm2[h]*relu(Wm1[h]*d+bm1[h])
// into a 64-breakpoint piecewise-linear table: sorted thresholds T[64] and
// per-segment (alpha,beta) with m(d)=alpha*d+beta. One wave. Bitonic sort in
// registers; segment coefficients via midpoint activity test (comparisons
// only -> no inf*0 NaN hazards).
// ---------------------------------------------------------------------------
__global__ __launch_bounds__(64) void prep_kernel(
    const float* __restrict__ Wm1, const float* __restrict__ bm1,
    const float* __restrict__ Wm2, const float* __restrict__ bm2,
    float* __restrict__ ws)
{
    const int lane = threadIdx.x;          // 0..63
    __shared__ float lw[HH], lb[HH], lm2[HH], lt[HH], ls[HH];

    float w = Wm1[lane];
    float b = bm1[lane];
    float m2 = Wm2[lane];
    float t = (w != 0.f) ? (-b / w) : INF; // finite for w!=0 (b finite)
    lw[lane] = w; lb[lane] = b; lm2[lane] = m2; lt[lane] = t;

    // bitonic sort of t across 64 lanes (ascending)
    float v = t;
#pragma unroll
    for (int k = 2; k <= 64; k <<= 1) {
#pragma unroll
        for (int j = k >> 1; j >= 1; j >>= 1) {
            float o = __shfl_xor(v, j);
            bool up = ((lane & k) == 0);
            bool lower = ((lane & j) == 0);
            float mn = fminf(v, o), mx = fmaxf(v, o);
            v = (up == lower) ? mn : mx;
        }
    }
    ls[lane] = v;
    ws[WS_T + lane] = v;
    __syncthreads();

    const float bm2v = bm2[0];
    // 65 segments; lane k does segment k, lane 0 also does segment 64.
    for (int k = lane; k < 65; k += 64) {
        float lo = (k == 0) ? -INF : ls[k - 1];
        float hi = (k == 64) ? INF : ls[k];
        float dt;
        if (k == 0) {
            dt = (hi == INF) ? 0.f : hi - 1.f;
        } else if (hi == INF) {
            dt = (lo == INF) ? INF : lo + 1.f;   // lo==INF: zero-width, never selected
        } else {
            dt = 0.5f * (lo + hi);
        }
        float alpha = 0.f, beta = bm2v;
#pragma unroll 8
        for (int h = 0; h < HH; ++h) {
            float wh = lw[h], bh = lb[h], mh = lm2[h], th = lt[h];
            // active(h) at d=dt, comparisons only (dt may be +inf)
            bool act = (wh > 0.f) ? (dt > th)
                     : ((wh < 0.f) ? (dt < th) : (bh > 0.f));
            if (act) {
                alpha = fmaf(mh, wh, alpha);
                beta  = fmaf(mh, bh, beta);
            }
        }
        ws[WS_A + k] = alpha;
        ws[WS_B + k] = beta;
    }
}

// ---------------------------------------------------------------------------
// Kernel A: g[n,c] = sum_f ( sum_h relu(x[n,f]*W1[f,h]+b1[f,h]) * W2[f,h,c] )
//                    + sum_f b2[f,c]
// One wave handles NB nodes; lane = h.
// ---------------------------------------------------------------------------
__global__ __launch_bounds__(256) void g_kernel(
    const float* __restrict__ x, const float* __restrict__ W1,
    const float* __restrict__ b1, const float* __restrict__ W2,
    const float* __restrict__ b2, float* __restrict__ g)
{
    const int wave = (blockIdx.x * 256 + threadIdx.x) >> 6;
    const int lane = threadIdx.x & 63;  // = h
    const int n0 = wave * NB;

    float xr[NB];
#pragma unroll
    for (int j = 0; j < NB; ++j) xr[j] = x[(n0 + j) * FF + lane];

    float acc[NB][CC];
#pragma unroll
    for (int j = 0; j < NB; ++j)
#pragma unroll
        for (int c = 0; c < CC; ++c) acc[j][c] = 0.f;

    float bs[CC];
    {
        const float4* bp = (const float4*)&b2[lane * CC];
        float4 a = bp[0], b = bp[1];
        bs[0] = a.x; bs[1] = a.y; bs[2] = a.z; bs[3] = a.w;
        bs[4] = b.x; bs[5] = b.y; bs[6] = b.z; bs[7] = b.w;
    }

#pragma unroll 4
    for (int f = 0; f < FF; ++f) {
        float w1 = W1[f * HH + lane];
        float bb = b1[f * HH + lane];
        const float4* w2p = (const float4*)&W2[(f * HH + lane) * CC];
        float4 wa = w2p[0];
        float4 wb = w2p[1];
#pragma unroll
        for (int j = 0; j < NB; ++j) {
            float xv = __shfl(xr[j], f);
            float hv = fmaxf(fmaf(xv, w1, bb), 0.f);
            acc[j][0] = fmaf(hv, wa.x, acc[j][0]);
            acc[j][1] = fmaf(hv, wa.y, acc[j][1]);
            acc[j][2] = fmaf(hv, wa.z, acc[j][2]);
            acc[j][3] = fmaf(hv, wa.w, acc[j][3]);
            acc[j][4] = fmaf(hv, wb.x, acc[j][4]);
            acc[j][5] = fmaf(hv, wb.y, acc[j][5]);
            acc[j][6] = fmaf(hv, wb.z, acc[j][6]);
            acc[j][7] = fmaf(hv, wb.w, acc[j][7]);
        }
    }

#pragma unroll
    for (int s = 32; s >= 1; s >>= 1) {
#pragma unroll
        for (int j = 0; j < NB; ++j)
#pragma unroll
            for (int c = 0; c < CC; ++c)
                acc[j][c] += __shfl_xor(acc[j][c], s);
#pragma unroll
        for (int c = 0; c < CC; ++c)
            bs[c] += __shfl_xor(bs[c], s);
    }

    if (lane == 0) {
#pragma unroll
        for (int j = 0; j < NB; ++j)
#pragma unroll
            for (int c = 0; c < CC; ++c)
                g[(n0 + j) * CC + c] = acc[j][c] + bs[c];
    }
}

// ---------------------------------------------------------------------------
// Kernel B: out[i,c] = sum_j m(i,j) * g[j,c]
// m via piecewise-linear table: binary search over T[64] (LDS), m=alpha*d+beta.
// One block per row i; thread t owns 8 j's as two float4 groups (coalesced).
// ---------------------------------------------------------------------------
__global__ __launch_bounds__(256) void out_kernel(
    const float* __restrict__ nd, const float* __restrict__ nm,
    const float* __restrict__ ws, const float* __restrict__ g,
    float* __restrict__ out)
{
    const int i = blockIdx.x;
    const int t = threadIdx.x;

    __shared__ float Tl[64], Al[65], Bl[65];
    if (t < 64) Tl[t] = ws[WS_T + t];
    else if (t < 129) Al[t - 64] = ws[WS_A + (t - 64)];
    else if (t < 194) Bl[t - 129] = ws[WS_B + (t - 129)];
    __syncthreads();

    // load 8 d's: two float4 per array, coalesced
    const float4* nd4 = (const float4*)(nd + (size_t)i * NN);
    const float4* nm4 = (const float4*)(nm + (size_t)i * NN);
    float dv[8];
#pragma unroll
    for (int p = 0; p < 2; ++p) {
        float4 a = nd4[p * 256 + t];
        float4 b = nm4[p * 256 + t];
        float na[4] = {a.x, a.y, a.z, a.w};
        float nb[4] = {b.x, b.y, b.z, b.w};
#pragma unroll
        for (int e = 0; e < 4; ++e) {
            float r = __builtin_amdgcn_rcpf(nb[e]);
            r = r * fmaf(-nb[e], r, 2.0f);     // 1 Newton step
            dv[p * 4 + e] = na[e] * r;
        }
    }

    float acc[CC];
#pragma unroll
    for (int c = 0; c < CC; ++c) acc[c] = 0.f;

#pragma unroll
    for (int p = 0; p < 2; ++p) {
#pragma unroll
        for (int e = 0; e < 4; ++e) {
            float d = dv[p * 4 + e];
            // branchless lower_bound over 64 sorted thresholds
            int lo = 0;
#pragma unroll
            for (int s = 32; s >= 1; s >>= 1)
                lo += (Tl[lo + s - 1] < d) ? s : 0;
            lo += (Tl[lo] < d) ? 1 : 0;        // final probe -> lo in [0,64]
            float m = fmaf(d, Al[lo], Bl[lo]);

            int j = p * 1024 + t * 4 + e;
            const float4* gp = (const float4*)&g[j * CC];
            float4 ga = gp[0];
            float4 gb = gp[1];
            acc[0] = fmaf(m, ga.x, acc[0]);
            acc[1] = fmaf(m, ga.y, acc[1]);
            acc[2] = fmaf(m, ga.z, acc[2]);
            acc[3] = fmaf(m, ga.w, acc[3]);
            acc[4] = fmaf(m, gb.x, acc[4]);
            acc[5] = fmaf(m, gb.y, acc[5]);
            acc[6] = fmaf(m, gb.z, acc[6]);
            acc[7] = fmaf(m, gb.w, acc[7]);
        }
    }

#pragma unroll
    for (int s = 32; s >= 1; s >>= 1) {
#pragma unroll
        for (int c = 0; c < CC; ++c)
            acc[c] += __shfl_xor(acc[c], s);
    }

    __shared__ float red[4][CC];
    const int wv = t >> 6;
    const int lane = t & 63;
    if (lane == 0) {
#pragma unroll
        for (int c = 0; c < CC; ++c) red[wv][c] = acc[c];
    }
    __syncthreads();
    if (t < CC) {
        out[i * CC + t] = red[0][t] + red[1][t] + red[2][t] + red[3][t];
    }
}

extern "C" void kernel_launch(void* const* d_in, const int* in_sizes, int n_in,
                              void* d_out, int out_size, void* d_ws, size_t ws_size,
                              hipStream_t stream) {
    const float* x   = (const float*)d_in[0];
    const float* nd  = (const float*)d_in[1];
    const float* nm  = (const float*)d_in[2];
    const float* W1  = (const float*)d_in[3];
    const float* b1  = (const float*)d_in[4];
    const float* W2  = (const float*)d_in[5];
    const float* b2  = (const float*)d_in[6];
    const float* Wm1 = (const float*)d_in[7];
    const float* bm1 = (const float*)d_in[8];
    const float* Wm2 = (const float*)d_in[9];
    const float* bm2 = (const float*)d_in[10];
    float* out = (float*)d_out;
    float* ws  = (float*)d_ws;

    prep_kernel<<<1, 64, 0, stream>>>(Wm1, bm1, Wm2, bm2, ws);
    g_kernel<<<NN / (NB * 4), 256, 0, stream>>>(x, W1, b1, W2, b2, ws + WS_G);
    out_kernel<<<NN, 256, 0, stream>>>(nd, nm, ws, ws + WS_G, out);
}

// Round 3
// 119.316 us; speedup vs baseline: 1.2257x; 1.2257x over previous
//
#include <hip/hip_runtime.h>

// Problem constants (fixed by the reference)
#define NN 2048   // nodes
#define FF 64     // features
#define HH 64     // hidden
#define CC 8      // classes
#define NB 2      // nodes per wave in g phase

#define INF __builtin_inff()

// ws layout (floats): T[64] @0, A[65] @64, B[65] @129, g[NN*CC] @256
#define WS_T 0
#define WS_A 64
#define WS_B 129
#define WS_G 256

// ---------------------------------------------------------------------------
// Fused kernel 1 (grid = 257 blocks of 256):
//   blocks 0..255 : g[n,c] = sum_f( sum_h relu(x[n,f]*W1[f,h]+b1[f,h])*W2[f,h,c] )
//                   + sum_f b2[f,c]           (wave-per-2-nodes, lane = h)
//   block 256     : collapse distance-MLP m(d) into a 64-breakpoint
//                   piecewise-linear table (sorted T[64], per-segment
//                   alpha/beta with m(d)=alpha*d+beta). Single wave,
//                   shuffle-only (no LDS, no __syncthreads) so waves 1..3
//                   can exit early without barrier UB.
// prep and g are independent; out_kernel consumes both.
// ---------------------------------------------------------------------------
__global__ __launch_bounds__(256) void fused1_kernel(
    const float* __restrict__ x, const float* __restrict__ W1,
    const float* __restrict__ b1, const float* __restrict__ W2,
    const float* __restrict__ b2,
    const float* __restrict__ Wm1, const float* __restrict__ bm1,
    const float* __restrict__ Wm2, const float* __restrict__ bm2,
    float* __restrict__ ws)
{
    if (blockIdx.x == 256) {
        // ---------------- prep: single wave, shuffle-only ----------------
        if (threadIdx.x >= 64) return;
        const int lane = threadIdx.x;

        float w  = Wm1[lane];
        float b  = bm1[lane];
        float m2 = Wm2[lane];
        float th = (w != 0.f) ? (-b / w) : INF;   // breakpoint of unit `lane`

        // bitonic sort of th across 64 lanes (ascending) -> v = sorted[lane]
        float v = th;
#pragma unroll
        for (int k = 2; k <= 64; k <<= 1) {
#pragma unroll
            for (int j = k >> 1; j >= 1; j >>= 1) {
                float o = __shfl_xor(v, j);
                bool up = ((lane & k) == 0);
                bool lower = ((lane & j) == 0);
                float mn = fminf(v, o), mx = fmaxf(v, o);
                v = (up == lower) ? mn : mx;
            }
        }
        ws[WS_T + lane] = v;

        // segment k = lane covers (T[k-1], T[k]); segment 64 = (T[63], inf)
        float lo  = __shfl_up(v, 1);              // T[lane-1] (garbage lane 0)
        float hi  = v;                            // T[lane]
        float t63 = __shfl(v, 63);                // T[63]

        float dt;
        if (lane == 0) dt = (hi == INF) ? 0.f : hi - 1.f;
        else if (hi == INF) dt = (lo == INF) ? INF : lo + 1.f;  // empty if lo inf
        else dt = 0.5f * (lo + hi);
        float dt64 = (t63 == INF) ? INF : t63 + 1.f;

        const float bm2v = bm2[0];
        float alpha = 0.f, beta = bm2v;           // segment `lane`
        float a64 = 0.f, b64 = bm2v;              // segment 64 (all lanes, redundant)
#pragma unroll 8
        for (int h = 0; h < HH; ++h) {
            float wh = __shfl(w, h);
            float bh = __shfl(b, h);
            float mh = __shfl(m2, h);
            float tt = __shfl(th, h);
            // unit h active at d: comparisons only (d may be +/-inf)
            bool act = (wh > 0.f) ? (dt > tt)
                     : ((wh < 0.f) ? (dt < tt) : (bh > 0.f));
            if (act) { alpha = fmaf(mh, wh, alpha); beta = fmaf(mh, bh, beta); }
            bool act64 = (wh > 0.f) ? (dt64 > tt)
                       : ((wh < 0.f) ? (dt64 < tt) : (bh > 0.f));
            if (act64) { a64 = fmaf(mh, wh, a64); b64 = fmaf(mh, bh, b64); }
        }
        ws[WS_A + lane] = alpha;
        ws[WS_B + lane] = beta;
        if (lane == 0) { ws[WS_A + 64] = a64; ws[WS_B + 64] = b64; }
        return;
    }

    // ---------------- g phase: blocks 0..255, no LDS ----------------
    float* g = ws + WS_G;
    const int wave = (blockIdx.x * 256 + threadIdx.x) >> 6;
    const int lane = threadIdx.x & 63;  // = h
    const int n0 = wave * NB;

    float xr[NB];
#pragma unroll
    for (int j = 0; j < NB; ++j) xr[j] = x[(n0 + j) * FF + lane];

    float acc[NB][CC];
#pragma unroll
    for (int j = 0; j < NB; ++j)
#pragma unroll
        for (int c = 0; c < CC; ++c) acc[j][c] = 0.f;

    float bs[CC];
    {
        const float4* bp = (const float4*)&b2[lane * CC];
        float4 a = bp[0], b = bp[1];
        bs[0] = a.x; bs[1] = a.y; bs[2] = a.z; bs[3] = a.w;
        bs[4] = b.x; bs[5] = b.y; bs[6] = b.z; bs[7] = b.w;
    }

#pragma unroll 4
    for (int f = 0; f < FF; ++f) {
        float w1 = W1[f * HH + lane];
        float bb = b1[f * HH + lane];
        const float4* w2p = (const float4*)&W2[(f * HH + lane) * CC];
        float4 wa = w2p[0];
        float4 wb = w2p[1];
#pragma unroll
        for (int j = 0; j < NB; ++j) {
            float xv = __shfl(xr[j], f);
            float hv = fmaxf(fmaf(xv, w1, bb), 0.f);
            acc[j][0] = fmaf(hv, wa.x, acc[j][0]);
            acc[j][1] = fmaf(hv, wa.y, acc[j][1]);
            acc[j][2] = fmaf(hv, wa.z, acc[j][2]);
            acc[j][3] = fmaf(hv, wa.w, acc[j][3]);
            acc[j][4] = fmaf(hv, wb.x, acc[j][4]);
            acc[j][5] = fmaf(hv, wb.y, acc[j][5]);
            acc[j][6] = fmaf(hv, wb.z, acc[j][6]);
            acc[j][7] = fmaf(hv, wb.w, acc[j][7]);
        }
    }

#pragma unroll
    for (int s = 32; s >= 1; s >>= 1) {
#pragma unroll
        for (int j = 0; j < NB; ++j)
#pragma unroll
            for (int c = 0; c < CC; ++c)
                acc[j][c] += __shfl_xor(acc[j][c], s);
#pragma unroll
        for (int c = 0; c < CC; ++c)
            bs[c] += __shfl_xor(bs[c], s);
    }

    if (lane == 0) {
#pragma unroll
        for (int j = 0; j < NB; ++j)
#pragma unroll
            for (int c = 0; c < CC; ++c)
                g[(n0 + j) * CC + c] = acc[j][c] + bs[c];
    }
}

// ---------------------------------------------------------------------------
// Kernel 2: out[i,c] = sum_j m(i,j) * g[j,c]
// m via piecewise-linear table: branchless binary search over T[64] in LDS,
// m = alpha*d + beta. One block per row i; thread t owns 8 j's as two float4
// groups (coalesced nd/nm loads, HBM-bound: 33.5 MB total).
// ---------------------------------------------------------------------------
__global__ __launch_bounds__(256) void out_kernel(
    const float* __restrict__ nd, const float* __restrict__ nm,
    const float* __restrict__ ws, const float* __restrict__ g,
    float* __restrict__ out)
{
    const int i = blockIdx.x;
    const int t = threadIdx.x;

    __shared__ float Tl[64], Al[65], Bl[65];
    if (t < 64) Tl[t] = ws[WS_T + t];
    else if (t < 129) Al[t - 64] = ws[WS_A + (t - 64)];
    else if (t < 194) Bl[t - 129] = ws[WS_B + (t - 129)];
    __syncthreads();

    const float4* nd4 = (const float4*)(nd + (size_t)i * NN);
    const float4* nm4 = (const float4*)(nm + (size_t)i * NN);
    float dv[8];
#pragma unroll
    for (int p = 0; p < 2; ++p) {
        float4 a = nd4[p * 256 + t];
        float4 b = nm4[p * 256 + t];
        float na[4] = {a.x, a.y, a.z, a.w};
        float nb[4] = {b.x, b.y, b.z, b.w};
#pragma unroll
        for (int e = 0; e < 4; ++e) {
            float r = __builtin_amdgcn_rcpf(nb[e]);
            r = r * fmaf(-nb[e], r, 2.0f);     // 1 Newton step
            dv[p * 4 + e] = na[e] * r;
        }
    }

    float acc[CC];
#pragma unroll
    for (int c = 0; c < CC; ++c) acc[c] = 0.f;

#pragma unroll
    for (int p = 0; p < 2; ++p) {
#pragma unroll
        for (int e = 0; e < 4; ++e) {
            float d = dv[p * 4 + e];
            // branchless lower_bound over 64 sorted thresholds -> lo in [0,64]
            int lo = 0;
#pragma unroll
            for (int s = 32; s >= 1; s >>= 1)
                lo += (Tl[lo + s - 1] < d) ? s : 0;
            lo += (Tl[lo] < d) ? 1 : 0;
            float m = fmaf(d, Al[lo], Bl[lo]);

            int j = p * 1024 + t * 4 + e;
            const float4* gp = (const float4*)&g[j * CC];
            float4 ga = gp[0];
            float4 gb = gp[1];
            acc[0] = fmaf(m, ga.x, acc[0]);
            acc[1] = fmaf(m, ga.y, acc[1]);
            acc[2] = fmaf(m, ga.z, acc[2]);
            acc[3] = fmaf(m, ga.w, acc[3]);
            acc[4] = fmaf(m, gb.x, acc[4]);
            acc[5] = fmaf(m, gb.y, acc[5]);
            acc[6] = fmaf(m, gb.z, acc[6]);
            acc[7] = fmaf(m, gb.w, acc[7]);
        }
    }

#pragma unroll
    for (int s = 32; s >= 1; s >>= 1) {
#pragma unroll
        for (int c = 0; c < CC; ++c)
            acc[c] += __shfl_xor(acc[c], s);
    }

    __shared__ float red[4][CC];
    const int wv = t >> 6;
    const int lane = t & 63;
    if (lane == 0) {
#pragma unroll
        for (int c = 0; c < CC; ++c) red[wv][c] = acc[c];
    }
    __syncthreads();
    if (t < CC) {
        out[i * CC + t] = red[0][t] + red[1][t] + red[2][t] + red[3][t];
    }
}

extern "C" void kernel_launch(void* const* d_in, const int* in_sizes, int n_in,
                              void* d_out, int out_size, void* d_ws, size_t ws_size,
                              hipStream_t stream) {
    const float* x   = (const float*)d_in[0];
    const float* nd  = (const float*)d_in[1];
    const float* nm  = (const float*)d_in[2];
    const float* W1  = (const float*)d_in[3];
    const float* b1  = (const float*)d_in[4];
    const float* W2  = (const float*)d_in[5];
    const float* b2  = (const float*)d_in[6];
    const float* Wm1 = (const float*)d_in[7];
    const float* bm1 = (const float*)d_in[8];
    const float* Wm2 = (const float*)d_in[9];
    const float* bm2 = (const float*)d_in[10];
    float* out = (float*)d_out;
    float* ws  = (float*)d_ws;

    fused1_kernel<<<257, 256, 0, stream>>>(x, W1, b1, W2, b2,
                                           Wm1, bm1, Wm2, bm2, ws);
    out_kernel<<<NN, 256, 0, stream>>>(nd, nm, ws, ws + WS_G, out);
}